// Round 1
// baseline (650.765 us; speedup 1.0000x reference)
//
#include <hip/hip_runtime.h>

typedef __bf16 bf16_t;
typedef __attribute__((ext_vector_type(8))) __bf16 bf16x8;
typedef __attribute__((ext_vector_type(4))) float f32x4;

#define M_DIM 8192   // BSZ*SEQ
#define N_DIM 4096   // OUT_DIM
#define K_DIM 4096   // IN_DIM
#define R_DIM 64     // total rank

// ---------------- kernel 1: x fp32 -> bf16 ----------------
__global__ __launch_bounds__(256) void cvt_x(const float* __restrict__ in,
                                             bf16_t* __restrict__ out) {
    size_t i = ((size_t)blockIdx.x * 256 + threadIdx.x) * 8;
    float4 a = *(const float4*)(in + i);
    float4 b = *(const float4*)(in + i + 4);
    bf16x8 v;
    v[0] = (bf16_t)a.x; v[1] = (bf16_t)a.y; v[2] = (bf16_t)a.z; v[3] = (bf16_t)a.w;
    v[4] = (bf16_t)b.x; v[5] = (bf16_t)b.y; v[6] = (bf16_t)b.z; v[7] = (bf16_t)b.w;
    *(bf16x8*)(out + i) = v;
}

// ------- kernel 2: Weff[o][i] = bf16(W[o][i] + sum_r (2*B[o][r])*A[r][i]) -------
// grid (K/256, N/16); thread owns column i, 16 rows o. B reads are block-uniform
// -> scalar loads; A column stays in 64 VGPRs (fp32 precision for the update).
__global__ __launch_bounds__(256) void build_weff(const float* __restrict__ W,
                                                  const float* __restrict__ A,
                                                  const float* __restrict__ Bl,
                                                  bf16_t* __restrict__ out) {
    const int i  = blockIdx.x * 256 + threadIdx.x;
    const int o0 = blockIdx.y * 16;
    float av[R_DIM];
#pragma unroll
    for (int r = 0; r < R_DIM; r++) av[r] = 2.0f * A[(size_t)r * K_DIM + i];
    for (int j = 0; j < 16; j++) {
        const int o = o0 + j;
        float acc = W[(size_t)o * K_DIM + i];
#pragma unroll
        for (int r = 0; r < R_DIM; r++) acc += Bl[o * R_DIM + r] * av[r];
        out[(size_t)o * K_DIM + i] = (bf16_t)acc;
    }
}

// ---------------- kernel 3: C[M][N] = Xb[M][K] * Weff[N][K]^T ----------------
#define BM 128
#define BN 128
#define BK 64   // 8 chunks of 8 bf16 (16 B) per row

// global -> LDS direct copy, 16 B per lane; LDS dest = wave-uniform base + lane*16
#define GLDS(gp, lp) __builtin_amdgcn_global_load_lds(                       \
    (__attribute__((address_space(1))) void*)(gp),                           \
    (__attribute__((address_space(3))) void*)(lp), 16, 0, 0)

__global__ __launch_bounds__(256) void gemm_bf16(const bf16_t* __restrict__ Ax,
                                                 const bf16_t* __restrict__ Bw,
                                                 float* __restrict__ C) {
    // XOR-swizzled tiles: LDS[r][c] holds global chunk (c ^ (r&7)) of row r.
    __shared__ __attribute__((aligned(16))) bf16_t Ash[BM * BK];
    __shared__ __attribute__((aligned(16))) bf16_t Bsh[BN * BK];

    const int tid  = threadIdx.x;
    const int wave = tid >> 6;
    const int lane = tid & 63;
    const int m16  = lane & 15;
    const int quad = lane >> 4;
    const int wm   = wave >> 1;   // 2x2 wave grid over the 128x128 tile
    const int wn   = wave & 1;
    const int m0 = blockIdx.y * BM;
    const int n0 = blockIdx.x * BN;

    f32x4 acc[4][4] = {};

    const int srow   = lane >> 3;  // row within 8-row staging group
    const int schunk = lane & 7;   // 16B chunk within row

    for (int k0 = 0; k0 < K_DIM; k0 += BK) {
        __syncthreads();  // previous tile fully consumed
#pragma unroll
        for (int i = 0; i < 4; i++) {
            const int rb = (i * 4 + wave) * 8;     // wave-uniform group base row
            const int r  = rb + srow;
            const int ca = schunk ^ (r & 7);       // source chunk for swizzle
            GLDS(Ax + (size_t)(m0 + r) * K_DIM + k0 + ca * 8, Ash + rb * BK);
            GLDS(Bw + (size_t)(n0 + r) * K_DIM + k0 + ca * 8, Bsh + rb * BK);
        }
        __syncthreads();  // vmcnt(0) drain -> tiles resident
#pragma unroll
        for (int ks = 0; ks < 2; ks++) {
            bf16x8 afr[4], bfr[4];
#pragma unroll
            for (int t = 0; t < 4; t++) {
                const int mr = wm * 64 + t * 16 + m16;
                const int nr = wn * 64 + t * 16 + m16;
                const int ck = ks * 4 + quad;      // logical 16B k-chunk
                afr[t] = *(const bf16x8*)(Ash + mr * BK + ((ck ^ (mr & 7)) << 3));
                bfr[t] = *(const bf16x8*)(Bsh + nr * BK + ((ck ^ (nr & 7)) << 3));
            }
#pragma unroll
            for (int tm = 0; tm < 4; tm++)
#pragma unroll
                for (int tn = 0; tn < 4; tn++)
                    acc[tm][tn] = __builtin_amdgcn_mfma_f32_16x16x32_bf16(
                        afr[tm], bfr[tn], acc[tm][tn], 0, 0, 0);
        }
    }

    // epilogue: C/D layout col = lane&15, row = quad*4 + reg
#pragma unroll
    for (int tm = 0; tm < 4; tm++) {
#pragma unroll
        for (int i = 0; i < 4; i++) {
            const int gm = m0 + wm * 64 + tm * 16 + quad * 4 + i;
            float* crow = C + (size_t)gm * N_DIM + n0 + wn * 64 + m16;
#pragma unroll
            for (int tn = 0; tn < 4; tn++)
                crow[tn * 16] = acc[tm][tn][i];
        }
    }
}

extern "C" void kernel_launch(void* const* d_in, const int* in_sizes, int n_in,
                              void* d_out, int out_size, void* d_ws, size_t ws_size,
                              hipStream_t stream) {
    const float* x  = (const float*)d_in[0];
    const float* W  = (const float*)d_in[1];
    const float* La = (const float*)d_in[2];
    const float* Lb = (const float*)d_in[3];
    float* out = (float*)d_out;

    // workspace: xb (64 MiB) | Weff (32 MiB)
    bf16_t* xb = (bf16_t*)d_ws;
    bf16_t* wf = (bf16_t*)((char*)d_ws + (size_t)M_DIM * K_DIM * sizeof(bf16_t));

    cvt_x<<<(M_DIM * K_DIM) / (256 * 8), 256, 0, stream>>>(x, xb);
    build_weff<<<dim3(K_DIM / 256, N_DIM / 16), 256, 0, stream>>>(W, La, Lb, wf);
    gemm_bf16<<<dim3(N_DIM / BN, M_DIM / BM), 256, 0, stream>>>(xb, wf, out);
}

// Round 2
// 609.662 us; speedup vs baseline: 1.0674x; 1.0674x over previous
//
#include <hip/hip_runtime.h>

typedef __bf16 bf16_t;
typedef __attribute__((ext_vector_type(8))) __bf16 bf16x8;
typedef __attribute__((ext_vector_type(4))) float f32x4;

#define M_DIM 8192   // BSZ*SEQ
#define N_DIM 4096   // OUT_DIM
#define K_DIM 4096   // IN_DIM
#define R_DIM 64     // total rank

// ---------------- kernel 1: x fp32 -> bf16 ----------------
__global__ __launch_bounds__(256) void cvt_x(const float* __restrict__ in,
                                             bf16_t* __restrict__ out) {
    size_t i = ((size_t)blockIdx.x * 256 + threadIdx.x) * 8;
    float4 a = *(const float4*)(in + i);
    float4 b = *(const float4*)(in + i + 4);
    bf16x8 v;
    v[0] = (bf16_t)a.x; v[1] = (bf16_t)a.y; v[2] = (bf16_t)a.z; v[3] = (bf16_t)a.w;
    v[4] = (bf16_t)b.x; v[5] = (bf16_t)b.y; v[6] = (bf16_t)b.z; v[7] = (bf16_t)b.w;
    *(bf16x8*)(out + i) = v;
}

// ------- kernel 2: Weff[o][i] = bf16(W[o][i] + sum_r (2*B[o][r])*A[r][i]) -------
// Thread owns column i and 16 rows o. Rank dim processed in 4 chunks of 16 so
// peak live regs ~= acc[16] + av[16] + addressing (~48 VGPR) -> no scratch
// spill (round-1 version held av[64] and almost certainly spilled: ~300us for
// a ~25us-roofline kernel). Bl reads are block-uniform -> scalar loads.
__global__ __launch_bounds__(256) void build_weff(const float* __restrict__ W,
                                                  const float* __restrict__ A,
                                                  const float* __restrict__ Bl,
                                                  bf16_t* __restrict__ out) {
    const int i  = blockIdx.x * 256 + threadIdx.x;
    const int o0 = blockIdx.y * 16;

    float acc[16];
#pragma unroll
    for (int j = 0; j < 16; j++) acc[j] = W[(size_t)(o0 + j) * K_DIM + i];

    for (int rh = 0; rh < R_DIM; rh += 16) {   // NOT unrolled: keeps pressure low
        float av[16];
#pragma unroll
        for (int r = 0; r < 16; r++) av[r] = 2.0f * A[(size_t)(rh + r) * K_DIM + i];
#pragma unroll
        for (int j = 0; j < 16; j++) {
#pragma unroll
            for (int r = 0; r < 16; r++)
                acc[j] += Bl[(o0 + j) * R_DIM + rh + r] * av[r];
        }
    }
#pragma unroll
    for (int j = 0; j < 16; j++) out[(size_t)(o0 + j) * K_DIM + i] = (bf16_t)acc[j];
}

// ---------------- kernel 3: C[M][N] = Xb[M][K] * Weff[N][K]^T ----------------
#define BM 128
#define BN 128
#define BK 64   // 8 chunks of 8 bf16 (16 B) per row

// global -> LDS direct copy, 16 B per lane; LDS dest = wave-uniform base + lane*16
#define GLDS(gp, lp) __builtin_amdgcn_global_load_lds(                       \
    (__attribute__((address_space(1))) void*)(gp),                           \
    (__attribute__((address_space(3))) void*)(lp), 16, 0, 0)

__global__ __launch_bounds__(256) void gemm_bf16(const bf16_t* __restrict__ Ax,
                                                 const bf16_t* __restrict__ Bw,
                                                 float* __restrict__ C) {
    // XOR-swizzled tiles: LDS[r][c] holds global chunk (c ^ (r&7)) of row r.
    __shared__ __attribute__((aligned(16))) bf16_t Ash[BM * BK];
    __shared__ __attribute__((aligned(16))) bf16_t Bsh[BN * BK];

    const int tid  = threadIdx.x;
    const int wave = tid >> 6;
    const int lane = tid & 63;
    const int m16  = lane & 15;
    const int quad = lane >> 4;
    const int wm   = wave >> 1;   // 2x2 wave grid over the 128x128 tile
    const int wn   = wave & 1;
    const int m0 = blockIdx.y * BM;
    const int n0 = blockIdx.x * BN;

    f32x4 acc[4][4] = {};

    const int srow   = lane >> 3;  // row within 8-row staging group
    const int schunk = lane & 7;   // 16B chunk within row

    for (int k0 = 0; k0 < K_DIM; k0 += BK) {
        __syncthreads();  // previous tile fully consumed
#pragma unroll
        for (int i = 0; i < 4; i++) {
            const int rb = (i * 4 + wave) * 8;     // wave-uniform group base row
            const int r  = rb + srow;
            const int ca = schunk ^ (r & 7);       // source chunk for swizzle
            GLDS(Ax + (size_t)(m0 + r) * K_DIM + k0 + ca * 8, Ash + rb * BK);
            GLDS(Bw + (size_t)(n0 + r) * K_DIM + k0 + ca * 8, Bsh + rb * BK);
        }
        __syncthreads();  // vmcnt(0) drain -> tiles resident
#pragma unroll
        for (int ks = 0; ks < 2; ks++) {
            bf16x8 afr[4], bfr[4];
#pragma unroll
            for (int t = 0; t < 4; t++) {
                const int mr = wm * 64 + t * 16 + m16;
                const int nr = wn * 64 + t * 16 + m16;
                const int ck = ks * 4 + quad;      // logical 16B k-chunk
                afr[t] = *(const bf16x8*)(Ash + mr * BK + ((ck ^ (mr & 7)) << 3));
                bfr[t] = *(const bf16x8*)(Bsh + nr * BK + ((ck ^ (nr & 7)) << 3));
            }
#pragma unroll
            for (int tm = 0; tm < 4; tm++)
#pragma unroll
                for (int tn = 0; tn < 4; tn++)
                    acc[tm][tn] = __builtin_amdgcn_mfma_f32_16x16x32_bf16(
                        afr[tm], bfr[tn], acc[tm][tn], 0, 0, 0);
        }
    }

    // epilogue: C/D layout col = lane&15, row = quad*4 + reg
#pragma unroll
    for (int tm = 0; tm < 4; tm++) {
#pragma unroll
        for (int i = 0; i < 4; i++) {
            const int gm = m0 + wm * 64 + tm * 16 + quad * 4 + i;
            float* crow = C + (size_t)gm * N_DIM + n0 + wn * 64 + m16;
#pragma unroll
            for (int tn = 0; tn < 4; tn++)
                crow[tn * 16] = acc[tm][tn][i];
        }
    }
}

extern "C" void kernel_launch(void* const* d_in, const int* in_sizes, int n_in,
                              void* d_out, int out_size, void* d_ws, size_t ws_size,
                              hipStream_t stream) {
    const float* x  = (const float*)d_in[0];
    const float* W  = (const float*)d_in[1];
    const float* La = (const float*)d_in[2];
    const float* Lb = (const float*)d_in[3];
    float* out = (float*)d_out;

    // workspace: xb (64 MiB) | Weff (32 MiB)
    bf16_t* xb = (bf16_t*)d_ws;
    bf16_t* wf = (bf16_t*)((char*)d_ws + (size_t)M_DIM * K_DIM * sizeof(bf16_t));

    cvt_x<<<(M_DIM * K_DIM) / (256 * 8), 256, 0, stream>>>(x, xb);
    build_weff<<<dim3(K_DIM / 256, N_DIM / 16), 256, 0, stream>>>(W, La, Lb, wf);
    gemm_bf16<<<dim3(N_DIM / BN, M_DIM / BM), 256, 0, stream>>>(xb, wf, out);
}